// Round 8
// baseline (179.914 us; speedup 1.0000x reference)
//
#include <hip/hip_runtime.h>

// ---------------------------------------------------------------------------
// MultiHeadSelfAttention: B=2, S=2048, D=1024, H=16, hd=64, fp32 in/out.
// R8: R7 with the cvt_pkrtz builtin return-type fix (bit_cast via auto).
//     Flash attention KV-split x2 -> 4 blocks/CU, unnormalized f32 partials
//     + merge kernel; softmax tree reductions, pkrtz packing.
// ---------------------------------------------------------------------------

typedef _Float16 f16;
typedef __attribute__((ext_vector_type(8))) _Float16 f16x8;
typedef __attribute__((ext_vector_type(4))) _Float16 f16x4;
typedef __attribute__((ext_vector_type(16))) float f32x16;
typedef __attribute__((ext_vector_type(4))) float f32x4;

__device__ __forceinline__ unsigned int pkrtz(float a, float b) {
  auto r = __builtin_amdgcn_cvt_pkrtz(a, b);  // __fp16 ext_vector(2); low half = a
  return __builtin_bit_cast(unsigned int, r);
}

typedef __attribute__((address_space(1))) const void gconst_void;
typedef __attribute__((address_space(3))) void lds_void;
__device__ __forceinline__ void gload16(const void* src, void* dst) {
  __builtin_amdgcn_global_load_lds((gconst_void*)src, (lds_void*)dst, 16, 0, 0);
}

#define QSCALE 0.18033688f  // 0.125 * log2(e): softmax runs in exp2 domain

// ---------------------------------------------------------------------------
// prep: X fp32 -> f16
// ---------------------------------------------------------------------------
__global__ __launch_bounds__(256) void to_f16_kernel(
    const float* __restrict__ in, f16* __restrict__ out)
{
  const int i = (blockIdx.x * 256 + threadIdx.x) * 8;
  float4 a = *(const float4*)(in + i);
  float4 b = *(const float4*)(in + i + 4);
  f16x8 o;
  o[0] = (f16)a.x; o[1] = (f16)a.y; o[2] = (f16)a.z; o[3] = (f16)a.w;
  o[4] = (f16)b.x; o[5] = (f16)b.y; o[6] = (f16)b.z; o[7] = (f16)b.w;
  *(f16x8*)(out + i) = o;
}

// ---------------------------------------------------------------------------
// prep: W[K][N] fp32 -> Wt[N][K] f16 (transpose + convert), 32x32 tiles
// ---------------------------------------------------------------------------
__global__ __launch_bounds__(256) void tconv_kernel(
    const float* __restrict__ W0, const float* __restrict__ W1,
    const float* __restrict__ W2, const float* __restrict__ W3,
    f16* __restrict__ T0, f16* __restrict__ T1,
    f16* __restrict__ T2, f16* __restrict__ T3,
    int N, int K)
{
  const int z = blockIdx.z;
  const float* W = (z == 0) ? W0 : (z == 1) ? W1 : (z == 2) ? W2 : W3;
  f16* T = (z == 0) ? T0 : (z == 1) ? T1 : (z == 2) ? T2 : T3;

  __shared__ float t[32][33];
  const int r = threadIdx.x >> 3;
  const int c4 = (threadIdx.x & 7) << 2;
  const int n0 = blockIdx.x * 32, k0 = blockIdx.y * 32;

  float4 v = *(const float4*)(W + (size_t)(k0 + r) * N + n0 + c4);
  t[r][c4 + 0] = v.x; t[r][c4 + 1] = v.y; t[r][c4 + 2] = v.z; t[r][c4 + 3] = v.w;
  __syncthreads();

  f16x4 hv;
#pragma unroll
  for (int j = 0; j < 4; ++j) hv[j] = (f16)t[c4 + j][r];
  *(f16x4*)(T + (size_t)(n0 + r) * K + k0 + c4) = hv;
}

// ---------------------------------------------------------------------------
// f16 MFMA GEMM core: 128x128 tile, 4 waves, BK=32, fragment-major LDS.
// ---------------------------------------------------------------------------
__device__ __forceinline__ void gemm_core_f16(
    const f16* __restrict__ A, const f16* __restrict__ Bt,
    int Kdim, int bm, int bn, int wv, int lane, char* lds, f32x4 acc[4][4])
{
  char* LA = lds;
  char* LB = lds + 8192;

  const int wr = wv >> 1, wc = wv & 1;
  const int sr = lane & 15;
  const int sc = (lane >> 4) * 8;
  const int c0 = wv * 2;
  const size_t rowA0 = (size_t)(bm + c0 * 16 + sr) * Kdim + sc;
  const size_t rowA1 = rowA0 + (size_t)16 * Kdim;
  const size_t rowB0 = (size_t)(bn + c0 * 16 + sr) * Kdim + sc;
  const size_t rowB1 = rowB0 + (size_t)16 * Kdim;
  const size_t d0 = (size_t)c0 * 1024;
  const size_t d1 = (size_t)(c0 + 1) * 1024;

#pragma unroll
  for (int m = 0; m < 4; ++m)
#pragma unroll
    for (int n = 0; n < 4; ++n)
#pragma unroll
      for (int j = 0; j < 4; ++j) acc[m][n][j] = 0.f;

  for (int k0 = 0; k0 < Kdim; k0 += 32) {
    __syncthreads();
    gload16(A + rowA0 + k0, LA + d0);
    gload16(A + rowA1 + k0, LA + d1);
    gload16(Bt + rowB0 + k0, LB + d0);
    gload16(Bt + rowB1 + k0, LB + d1);
    __syncthreads();

    f16x8 a[4];
#pragma unroll
    for (int i = 0; i < 4; ++i)
      a[i] = *(const f16x8*)(LA + (wr * 4 + i) * 1024 + lane * 16);
#pragma unroll
    for (int n = 0; n < 4; ++n) {
      f16x8 b = *(const f16x8*)(LB + (wc * 4 + n) * 1024 + lane * 16);
#pragma unroll
      for (int m = 0; m < 4; ++m)
        acc[m][n] = __builtin_amdgcn_mfma_f32_16x16x32_f16(a[m], b, acc[m][n], 0, 0, 0);
    }
  }
}

// ---------------------------------------------------------------------------
// QKV GEMM, f16 epilogues (z=0 Q*QSCALE, z=1 K, z=2 V^T [bh][64][2048])
// ---------------------------------------------------------------------------
__global__ __launch_bounds__(256, 3) void gemm_qkv_f16(
    const f16* __restrict__ A,
    const f16* __restrict__ B0, const f16* __restrict__ B1, const f16* __restrict__ B2,
    const float* __restrict__ bias0, const float* __restrict__ bias1,
    const float* __restrict__ bias2,
    f16* __restrict__ Qh, f16* __restrict__ Kh, f16* __restrict__ Vtg,
    int M, int N, int Kdim)
{
  const int z = blockIdx.z;
  const f16* Bt = (z == 0) ? B0 : (z == 1) ? B1 : B2;
  const float* bias = (z == 0) ? bias0 : (z == 1) ? bias1 : bias2;

  __shared__ __align__(16) char lds[16384];
  const int tid = threadIdx.x;
  const int wv = tid >> 6, lane = tid & 63;
  const int wr = wv >> 1, wc = wv & 1;
  const int bm = blockIdx.y * 128, bn = blockIdx.x * 128;

  f32x4 acc[4][4];
  gemm_core_f16(A, Bt, Kdim, bm, bn, wv, lane, lds, acc);

  const int cn = lane & 15, cr4 = (lane >> 4) * 4;
  float bias_v[4];
#pragma unroll
  for (int n = 0; n < 4; ++n) bias_v[n] = bias[bn + wc * 64 + n * 16 + cn];

  if (z == 2) {
#pragma unroll
    for (int m = 0; m < 4; ++m) {
      const int r0 = bm + wr * 64 + m * 16 + cr4;
      const int bb = r0 >> 11, ss = r0 & 2047;
#pragma unroll
      for (int n = 0; n < 4; ++n) {
        const int col = bn + wc * 64 + n * 16 + cn;
        const int h = col >> 6, dh = col & 63;
        f16x4 pv;
#pragma unroll
        for (int j = 0; j < 4; ++j) pv[j] = (f16)(acc[m][n][j] + bias_v[n]);
        *(f16x4*)(Vtg + ((size_t)((bb << 4) + h) * 64 + dh) * 2048 + ss) = pv;
      }
    }
  } else {
    const float qs = (z == 0) ? QSCALE : 1.0f;
    f16* Dst = (z == 0) ? Qh : Kh;
#pragma unroll
    for (int m = 0; m < 4; ++m) {
#pragma unroll
      for (int n = 0; n < 4; ++n) {
        const size_t base = (size_t)(bm + wr * 64 + m * 16 + cr4) * N + bn + wc * 64 + n * 16 + cn;
#pragma unroll
        for (int j = 0; j < 4; ++j)
          Dst[base + (size_t)j * N] = (f16)((acc[m][n][j] + bias_v[n]) * qs);
      }
    }
  }
}

// ---------------------------------------------------------------------------
// output projection: fp32 epilogue + bias
// ---------------------------------------------------------------------------
__global__ __launch_bounds__(256, 3) void gemm_out_f16(
    const f16* __restrict__ A, const f16* __restrict__ Bt,
    const float* __restrict__ bias, float* __restrict__ C,
    int M, int N, int Kdim)
{
  __shared__ __align__(16) char lds[16384];
  const int tid = threadIdx.x;
  const int wv = tid >> 6, lane = tid & 63;
  const int wr = wv >> 1, wc = wv & 1;
  const int bm = blockIdx.y * 128, bn = blockIdx.x * 128;

  f32x4 acc[4][4];
  gemm_core_f16(A, Bt, Kdim, bm, bn, wv, lane, lds, acc);

  const int cn = lane & 15, cr4 = (lane >> 4) * 4;
  float bias_v[4];
#pragma unroll
  for (int n = 0; n < 4; ++n) bias_v[n] = bias[bn + wc * 64 + n * 16 + cn];
#pragma unroll
  for (int m = 0; m < 4; ++m) {
#pragma unroll
    for (int n = 0; n < 4; ++n) {
      float* cp = C + (size_t)(bm + wr * 64 + m * 16 + cr4) * N + bn + wc * 64 + n * 16 + cn;
#pragma unroll
      for (int j = 0; j < 4; ++j) cp[(size_t)j * N] = acc[m][n][j] + bias_v[n];
    }
  }
}

// ---------------------------------------------------------------------------
// Flash attention, KV-split x2. Each block: one (qt, bh, half) -> 1024 keys.
// Writes unnormalized O partial (f32), running max m and sum l per q-row.
// ---------------------------------------------------------------------------
#define KROW 144
#define OWST 68
#define NROW 65536  // 32 bh * 2048 q-rows

__global__ __launch_bounds__(256) void flash_f16_kernel(
    const f16* __restrict__ Qh, const f16* __restrict__ Kh,
    const f16* __restrict__ Vtg,
    float* __restrict__ Po, float* __restrict__ Pm, float* __restrict__ Pl)
{
  constexpr int S = 2048, D = 1024;
  __shared__ __align__(16) char smem[34816];
  char* KL  = smem;
  char* VtL = smem + 9216;
  float* Ow = (float*)smem;

  // XCD swizzle: 128 consecutive swz-blocks (4 bh-groups) per XCD
  const int lin = blockIdx.x;
  const int swz = (lin & 7) * 128 + (lin >> 3);
  const int qt = swz & 15;
  const int half = (swz >> 4) & 1;
  const int bh = swz >> 5;
  const int b = bh >> 4, h = bh & 15;
  const int kb0 = half << 10;

  const int tid = threadIdx.x;
  const int w = tid >> 6, lane = tid & 63;
  const int l31 = lane & 31, h5 = lane >> 5;

  // ---- Q fragments ----
  const int qrow = qt * 128 + w * 32 + l31;
  const size_t qbase = (size_t)(b * S + qrow) * D + h * 64;
  f16x8 qf[4];
#pragma unroll
  for (int t = 0; t < 4; ++t)
    qf[t] = *(const f16x8*)(Qh + qbase + 16 * t + 8 * h5);

  f32x16 o0, o1;
#pragma unroll
  for (int r = 0; r < 16; ++r) { o0[r] = 0.f; o1[r] = 0.f; }
  float m = -1e30f, lsum = 0.f;

  // staging: 2 keys / 2 d-rows per thread, 16B chunks, incremental pointers
  const int keyA = tid >> 3;
  const int off8 = (tid & 7) * 8;
  const f16* kp = Kh + (size_t)(b * S + kb0 + keyA) * D + h * 64 + off8;
  const f16* vp = Vtg + (size_t)bh * 64 * 2048 + (size_t)keyA * 2048 + kb0 + off8;

  const auto pv_step = [&](const f32x16& s, const int koff) {
#pragma unroll
    for (int tp = 0; tp < 2; ++tp) {
      unsigned int wA0 = pkrtz(s[8 * tp + 0], s[8 * tp + 1]);
      unsigned int wA1 = pkrtz(s[8 * tp + 2], s[8 * tp + 3]);
      unsigned int wB0 = pkrtz(s[8 * tp + 4], s[8 * tp + 5]);
      unsigned int wB1 = pkrtz(s[8 * tp + 6], s[8 * tp + 7]);
      unsigned int snd0 = h5 ? wA0 : wB0;
      unsigned int snd1 = h5 ? wA1 : wB1;
      unsigned int rc0 = (unsigned int)__shfl_xor((int)snd0, 32);
      unsigned int rc1 = (unsigned int)__shfl_xor((int)snd1, 32);
      union { f16x8 v; unsigned int u[4]; } pf;
      pf.u[0] = h5 ? rc0 : wA0;
      pf.u[1] = h5 ? rc1 : wA1;
      pf.u[2] = h5 ? wB0 : rc0;
      pf.u[3] = h5 ? wB1 : rc1;
      f16x8 v0 = *(const f16x8*)(VtL + l31 * KROW + koff + 32 * tp + 16 * h5);
      f16x8 v1 = *(const f16x8*)(VtL + (32 + l31) * KROW + koff + 32 * tp + 16 * h5);
      o0 = __builtin_amdgcn_mfma_f32_32x32x16_f16(v0, pf.v, o0, 0, 0, 0);
      o1 = __builtin_amdgcn_mfma_f32_32x32x16_f16(v1, pf.v, o1, 0, 0, 0);
    }
  };

  for (int it = 0; it < 16; ++it) {
    f16x8 rK0 = *(const f16x8*)kp;
    f16x8 rK1 = *(const f16x8*)(kp + (size_t)32 * D);
    f16x8 rV0 = *(const f16x8*)vp;
    f16x8 rV1 = *(const f16x8*)(vp + (size_t)32 * 2048);
    kp += (size_t)64 * D;
    vp += 64;

    __syncthreads();
    *(f16x8*)(KL + keyA * KROW + off8 * 2)         = rK0;
    *(f16x8*)(KL + (keyA + 32) * KROW + off8 * 2)  = rK1;
    *(f16x8*)(VtL + keyA * KROW + off8 * 2)        = rV0;
    *(f16x8*)(VtL + (keyA + 32) * KROW + off8 * 2) = rV1;
    __syncthreads();

    // ---- scores^T (exp2 domain) ----
    f32x16 s0, s1;
#pragma unroll
    for (int r = 0; r < 16; ++r) { s0[r] = 0.f; s1[r] = 0.f; }
#pragma unroll
    for (int t = 0; t < 4; ++t) {
      f16x8 a0 = *(const f16x8*)(KL + l31 * KROW + 32 * t + 16 * h5);
      f16x8 a1 = *(const f16x8*)(KL + (32 + l31) * KROW + 32 * t + 16 * h5);
      s0 = __builtin_amdgcn_mfma_f32_32x32x16_f16(a0, qf[t], s0, 0, 0, 0);
      s1 = __builtin_amdgcn_mfma_f32_32x32x16_f16(a1, qf[t], s1, 0, 0, 0);
    }

    // ---- online softmax with defer-max; tree reductions ----
    float mx[16];
#pragma unroll
    for (int r = 0; r < 16; ++r) mx[r] = fmaxf(s0[r], s1[r]);
#pragma unroll
    for (int st = 8; st >= 1; st >>= 1)
#pragma unroll
      for (int r = 0; r < st; ++r) mx[r] = fmaxf(mx[r], mx[r + st]);
    float tmax = fmaxf(mx[0], __shfl_xor(mx[0], 32));

    if (!__all(tmax - m <= 8.0f)) {
      const float mn = fmaxf(m, tmax);
      const float fr = exp2f(m - mn);
      lsum *= fr;
#pragma unroll
      for (int r = 0; r < 16; ++r) { o0[r] *= fr; o1[r] *= fr; }
      m = mn;
    }
#pragma unroll
    for (int r = 0; r < 16; ++r) s0[r] = exp2f(s0[r] - m);
#pragma unroll
    for (int r = 0; r < 16; ++r) s1[r] = exp2f(s1[r] - m);
    float tsum[16];
#pragma unroll
    for (int r = 0; r < 16; ++r) tsum[r] = s0[r] + s1[r];
#pragma unroll
    for (int st = 8; st >= 1; st >>= 1)
#pragma unroll
      for (int r = 0; r < st; ++r) tsum[r] += tsum[r + st];
    lsum += tsum[0] + __shfl_xor(tsum[0], 32);

    pv_step(s0, 0);
    pv_step(s1, 64);
  }

  // ---- write m/l (pair lanes hold identical values; h5==0 writes) ----
  const size_t grow = (size_t)bh * S + qrow;          // global q-row id
  if (h5 == 0) {
    Pm[(size_t)half * NROW + grow] = m;
    Pl[(size_t)half * NROW + grow] = lsum;
  }

  // ---- epilogue: O^T -> LDS transpose -> unnormalized f32 partial ----
  __syncthreads();
  float* owp = Ow + w * 32 * OWST;
#pragma unroll
  for (int r = 0; r < 16; ++r) {
    const int d = (r & 3) + 8 * (r >> 2) + 4 * h5;
    owp[l31 * OWST + d]      = o0[r];
    owp[l31 * OWST + d + 32] = o1[r];
  }
  __syncthreads();
  float* PoH = Po + (size_t)half * NROW * 64;
#pragma unroll
  for (int it = 0; it < 8; ++it) {
    const int row = it * 4 + (lane >> 4);
    const int col = (lane & 15) * 4;
    float4 val = *(float4*)(owp + row * OWST + col);
    const size_t gr = (size_t)bh * S + qt * 128 + w * 32 + row;
    *(float4*)(PoH + gr * 64 + col) = val;
  }
}

// ---------------------------------------------------------------------------
// merge the two KV-halves: out = (w1*o1 + w2*o2) / (w1*l1 + w2*l2), f16 to Cc
// ---------------------------------------------------------------------------
__global__ __launch_bounds__(256) void merge_kernel(
    const float* __restrict__ Po, const float* __restrict__ Pm,
    const float* __restrict__ Pl, f16* __restrict__ Cc)
{
  const int wid = threadIdx.x >> 6, lane = threadIdx.x & 63;
  const int rowBase = blockIdx.x * 256 + wid * 64;
#pragma unroll 4
  for (int i = 0; i < 64; ++i) {
    const int gr = rowBase + i;
    const float m1 = Pm[gr], m2 = Pm[NROW + gr];
    const float l1 = Pl[gr], l2 = Pl[NROW + gr];
    const float mm = fmaxf(m1, m2);
    const float w1 = exp2f(m1 - mm), w2 = exp2f(m2 - mm);
    const float o1 = Po[(size_t)gr * 64 + lane];
    const float o2 = Po[((size_t)NROW + gr) * 64 + lane];
    const float o = (w1 * o1 + w2 * o2) / (w1 * l1 + w2 * l2);
    const int bh = gr >> 11, row = gr & 2047;
    const int b = bh >> 4, h = bh & 15;
    Cc[(size_t)(b * 2048 + row) * 1024 + h * 64 + lane] = (f16)o;
  }
}

// ---------------------------------------------------------------------------

extern "C" void kernel_launch(void* const* d_in, const int* in_sizes, int n_in,
                              void* d_out, int out_size, void* d_ws, size_t ws_size,
                              hipStream_t stream) {
  const float* X  = (const float*)d_in[0];
  const float* Wq = (const float*)d_in[1];
  const float* bq = (const float*)d_in[2];
  const float* Wk = (const float*)d_in[3];
  const float* bk = (const float*)d_in[4];
  const float* Wv = (const float*)d_in[5];
  const float* bv = (const float*)d_in[6];
  const float* Wo = (const float*)d_in[7];
  const float* bo = (const float*)d_in[8];
  float* out = (float*)d_out;

  const int B = 2, S = 2048, D = 1024;
  const int M = B * S;                 // 4096
  const size_t MD = (size_t)M * D;     // 4M elements

  f16* Xh  = (f16*)d_ws;               // 8 MB each MD-sized f16 buffer
  f16* Qh  = Xh + MD;
  f16* Kh  = Qh + MD;
  f16* Vtg = Kh + MD;
  f16* Cc  = Vtg + MD;
  f16* Wt  = Cc + MD;                  // 4 x D*D f16 = 8 MB
  f16* Wts[4];
  for (int i = 0; i < 4; ++i) Wts[i] = Wt + (size_t)i * D * D;
  float* Po = (float*)(Wt + (size_t)4 * D * D);  // 2 x 65536 x 64 f32 = 33.5 MB
  float* Pm = Po + (size_t)2 * 65536 * 64;       // 0.5 MB
  float* Pl = Pm + (size_t)2 * 65536;            // 0.5 MB

  to_f16_kernel<<<dim3(MD / (256 * 8)), 256, 0, stream>>>(X, Xh);
  tconv_kernel<<<dim3(D / 32, D / 32, 4), 256, 0, stream>>>(
      Wq, Wk, Wv, Wo, Wts[0], Wts[1], Wts[2], Wts[3], D, D);

  gemm_qkv_f16<<<dim3(D / 128, M / 128, 3), 256, 0, stream>>>(
      Xh, Wts[0], Wts[1], Wts[2], bq, bk, bv, Qh, Kh, Vtg, M, D, D);

  flash_f16_kernel<<<dim3(1024), 256, 0, stream>>>(Qh, Kh, Vtg, Po, Pm, Pl);
  merge_kernel<<<dim3(256), 256, 0, stream>>>(Po, Pm, Pl, Cc);

  gemm_out_f16<<<dim3(D / 128, M / 128, 1), 256, 0, stream>>>(
      Cc, Wts[3], bo, out, M, D, D);
}

// Round 9
// 163.397 us; speedup vs baseline: 1.1011x; 1.1011x over previous
//
#include <hip/hip_runtime.h>

// ---------------------------------------------------------------------------
// MultiHeadSelfAttention: B=2, S=2048, D=1024, H=16, hd=64, fp32 in/out.
// R9: R6 structure (no KV-split; split/merge reverted — R8 showed issue-bound,
//     not latency-bound). Flash VALU trims:
//       - QK^T accumulator init = -m  (deletes 32 v_sub/tile, rel-domain softmax)
//       - permlane32_swap P-relayout  (replaces shfl_xor+cndmask select web)
//       - max3-fused reduction tree   (31 fmax -> ~16 ops)
// ---------------------------------------------------------------------------

typedef _Float16 f16;
typedef __attribute__((ext_vector_type(8))) _Float16 f16x8;
typedef __attribute__((ext_vector_type(4))) _Float16 f16x4;
typedef __attribute__((ext_vector_type(16))) float f32x16;
typedef __attribute__((ext_vector_type(4))) float f32x4;

__device__ __forceinline__ unsigned int pkrtz(float a, float b) {
  auto r = __builtin_amdgcn_cvt_pkrtz(a, b);  // low half = a
  return __builtin_bit_cast(unsigned int, r);
}

typedef __attribute__((address_space(1))) const void gconst_void;
typedef __attribute__((address_space(3))) void lds_void;
__device__ __forceinline__ void gload16(const void* src, void* dst) {
  __builtin_amdgcn_global_load_lds((gconst_void*)src, (lds_void*)dst, 16, 0, 0);
}

#define QSCALE 0.18033688f  // 0.125 * log2(e): softmax runs in exp2 domain

// ---------------------------------------------------------------------------
// prep: X fp32 -> f16
// ---------------------------------------------------------------------------
__global__ __launch_bounds__(256) void to_f16_kernel(
    const float* __restrict__ in, f16* __restrict__ out)
{
  const int i = (blockIdx.x * 256 + threadIdx.x) * 8;
  float4 a = *(const float4*)(in + i);
  float4 b = *(const float4*)(in + i + 4);
  f16x8 o;
  o[0] = (f16)a.x; o[1] = (f16)a.y; o[2] = (f16)a.z; o[3] = (f16)a.w;
  o[4] = (f16)b.x; o[5] = (f16)b.y; o[6] = (f16)b.z; o[7] = (f16)b.w;
  *(f16x8*)(out + i) = o;
}

// ---------------------------------------------------------------------------
// prep: W[K][N] fp32 -> Wt[N][K] f16 (transpose + convert), 32x32 tiles
// ---------------------------------------------------------------------------
__global__ __launch_bounds__(256) void tconv_kernel(
    const float* __restrict__ W0, const float* __restrict__ W1,
    const float* __restrict__ W2, const float* __restrict__ W3,
    f16* __restrict__ T0, f16* __restrict__ T1,
    f16* __restrict__ T2, f16* __restrict__ T3,
    int N, int K)
{
  const int z = blockIdx.z;
  const float* W = (z == 0) ? W0 : (z == 1) ? W1 : (z == 2) ? W2 : W3;
  f16* T = (z == 0) ? T0 : (z == 1) ? T1 : (z == 2) ? T2 : T3;

  __shared__ float t[32][33];
  const int r = threadIdx.x >> 3;
  const int c4 = (threadIdx.x & 7) << 2;
  const int n0 = blockIdx.x * 32, k0 = blockIdx.y * 32;

  float4 v = *(const float4*)(W + (size_t)(k0 + r) * N + n0 + c4);
  t[r][c4 + 0] = v.x; t[r][c4 + 1] = v.y; t[r][c4 + 2] = v.z; t[r][c4 + 3] = v.w;
  __syncthreads();

  f16x4 hv;
#pragma unroll
  for (int j = 0; j < 4; ++j) hv[j] = (f16)t[c4 + j][r];
  *(f16x4*)(T + (size_t)(n0 + r) * K + k0 + c4) = hv;
}

// ---------------------------------------------------------------------------
// f16 MFMA GEMM core: 128x128 tile, 4 waves, BK=32, fragment-major LDS.
// ---------------------------------------------------------------------------
__device__ __forceinline__ void gemm_core_f16(
    const f16* __restrict__ A, const f16* __restrict__ Bt,
    int Kdim, int bm, int bn, int wv, int lane, char* lds, f32x4 acc[4][4])
{
  char* LA = lds;
  char* LB = lds + 8192;

  const int wr = wv >> 1, wc = wv & 1;
  const int sr = lane & 15;
  const int sc = (lane >> 4) * 8;
  const int c0 = wv * 2;
  const size_t rowA0 = (size_t)(bm + c0 * 16 + sr) * Kdim + sc;
  const size_t rowA1 = rowA0 + (size_t)16 * Kdim;
  const size_t rowB0 = (size_t)(bn + c0 * 16 + sr) * Kdim + sc;
  const size_t rowB1 = rowB0 + (size_t)16 * Kdim;
  const size_t d0 = (size_t)c0 * 1024;
  const size_t d1 = (size_t)(c0 + 1) * 1024;

#pragma unroll
  for (int m = 0; m < 4; ++m)
#pragma unroll
    for (int n = 0; n < 4; ++n)
#pragma unroll
      for (int j = 0; j < 4; ++j) acc[m][n][j] = 0.f;

  for (int k0 = 0; k0 < Kdim; k0 += 32) {
    __syncthreads();
    gload16(A + rowA0 + k0, LA + d0);
    gload16(A + rowA1 + k0, LA + d1);
    gload16(Bt + rowB0 + k0, LB + d0);
    gload16(Bt + rowB1 + k0, LB + d1);
    __syncthreads();

    f16x8 a[4];
#pragma unroll
    for (int i = 0; i < 4; ++i)
      a[i] = *(const f16x8*)(LA + (wr * 4 + i) * 1024 + lane * 16);
#pragma unroll
    for (int n = 0; n < 4; ++n) {
      f16x8 b = *(const f16x8*)(LB + (wc * 4 + n) * 1024 + lane * 16);
#pragma unroll
      for (int m = 0; m < 4; ++m)
        acc[m][n] = __builtin_amdgcn_mfma_f32_16x16x32_f16(a[m], b, acc[m][n], 0, 0, 0);
    }
  }
}

// ---------------------------------------------------------------------------
// QKV GEMM, f16 epilogues (z=0 Q*QSCALE, z=1 K, z=2 V^T [bh][64][2048])
// ---------------------------------------------------------------------------
__global__ __launch_bounds__(256, 3) void gemm_qkv_f16(
    const f16* __restrict__ A,
    const f16* __restrict__ B0, const f16* __restrict__ B1, const f16* __restrict__ B2,
    const float* __restrict__ bias0, const float* __restrict__ bias1,
    const float* __restrict__ bias2,
    f16* __restrict__ Qh, f16* __restrict__ Kh, f16* __restrict__ Vtg,
    int M, int N, int Kdim)
{
  const int z = blockIdx.z;
  const f16* Bt = (z == 0) ? B0 : (z == 1) ? B1 : B2;
  const float* bias = (z == 0) ? bias0 : (z == 1) ? bias1 : bias2;

  __shared__ __align__(16) char lds[16384];
  const int tid = threadIdx.x;
  const int wv = tid >> 6, lane = tid & 63;
  const int wr = wv >> 1, wc = wv & 1;
  const int bm = blockIdx.y * 128, bn = blockIdx.x * 128;

  f32x4 acc[4][4];
  gemm_core_f16(A, Bt, Kdim, bm, bn, wv, lane, lds, acc);

  const int cn = lane & 15, cr4 = (lane >> 4) * 4;
  float bias_v[4];
#pragma unroll
  for (int n = 0; n < 4; ++n) bias_v[n] = bias[bn + wc * 64 + n * 16 + cn];

  if (z == 2) {
#pragma unroll
    for (int m = 0; m < 4; ++m) {
      const int r0 = bm + wr * 64 + m * 16 + cr4;
      const int bb = r0 >> 11, ss = r0 & 2047;
#pragma unroll
      for (int n = 0; n < 4; ++n) {
        const int col = bn + wc * 64 + n * 16 + cn;
        const int h = col >> 6, dh = col & 63;
        f16x4 pv;
#pragma unroll
        for (int j = 0; j < 4; ++j) pv[j] = (f16)(acc[m][n][j] + bias_v[n]);
        *(f16x4*)(Vtg + ((size_t)((bb << 4) + h) * 64 + dh) * 2048 + ss) = pv;
      }
    }
  } else {
    const float qs = (z == 0) ? QSCALE : 1.0f;
    f16* Dst = (z == 0) ? Qh : Kh;
#pragma unroll
    for (int m = 0; m < 4; ++m) {
#pragma unroll
      for (int n = 0; n < 4; ++n) {
        const size_t base = (size_t)(bm + wr * 64 + m * 16 + cr4) * N + bn + wc * 64 + n * 16 + cn;
#pragma unroll
        for (int j = 0; j < 4; ++j)
          Dst[base + (size_t)j * N] = (f16)((acc[m][n][j] + bias_v[n]) * qs);
      }
    }
  }
}

// ---------------------------------------------------------------------------
// output projection: fp32 epilogue + bias
// ---------------------------------------------------------------------------
__global__ __launch_bounds__(256, 3) void gemm_out_f16(
    const f16* __restrict__ A, const f16* __restrict__ Bt,
    const float* __restrict__ bias, float* __restrict__ C,
    int M, int N, int Kdim)
{
  __shared__ __align__(16) char lds[16384];
  const int tid = threadIdx.x;
  const int wv = tid >> 6, lane = tid & 63;
  const int wr = wv >> 1, wc = wv & 1;
  const int bm = blockIdx.y * 128, bn = blockIdx.x * 128;

  f32x4 acc[4][4];
  gemm_core_f16(A, Bt, Kdim, bm, bn, wv, lane, lds, acc);

  const int cn = lane & 15, cr4 = (lane >> 4) * 4;
  float bias_v[4];
#pragma unroll
  for (int n = 0; n < 4; ++n) bias_v[n] = bias[bn + wc * 64 + n * 16 + cn];
#pragma unroll
  for (int m = 0; m < 4; ++m) {
#pragma unroll
    for (int n = 0; n < 4; ++n) {
      float* cp = C + (size_t)(bm + wr * 64 + m * 16 + cr4) * N + bn + wc * 64 + n * 16 + cn;
#pragma unroll
      for (int j = 0; j < 4; ++j) cp[(size_t)j * N] = acc[m][n][j] + bias_v[n];
    }
  }
}

// ---------------------------------------------------------------------------
// MFMA flash attention, f16, rel-domain online softmax:
//   QK^T acc initialized to -m -> s regs hold (score - m) directly.
//   Defer-max guard (<=8 in log2); rescale branch adjusts s, o, lsum, -m.
//   P-relayout via permlane32_swap (2 per k-slice). KVBLK=64.
// ---------------------------------------------------------------------------
#define KROW 144
#define OWST 68

__global__ __launch_bounds__(256) void flash_f16_kernel(
    const f16* __restrict__ Qh, const f16* __restrict__ Kh,
    const f16* __restrict__ Vtg, f16* __restrict__ Cc)
{
  constexpr int S = 2048, D = 1024;
  __shared__ __align__(16) char smem[34816];
  char* KL  = smem;                 // 64*144 = 9216
  char* VtL = smem + 9216;          // 9216
  float* Ow = (float*)smem;         // epilogue reuse

  // XCD swizzle: 64 consecutive blocks (4 heads) per XCD
  const int lin = blockIdx.y * 16 + blockIdx.x;
  const int swz = (lin & 7) * 64 + (lin >> 3);
  const int qt = swz & 15;
  const int bh = swz >> 4;
  const int b = bh >> 4, h = bh & 15;

  const int tid = threadIdx.x;
  const int w = tid >> 6, lane = tid & 63;
  const int l31 = lane & 31, h5 = lane >> 5;

  // ---- Q fragments (pre-scaled f16) ----
  const int qrow = qt * 128 + w * 32 + l31;
  const size_t qbase = (size_t)(b * S + qrow) * D + h * 64;
  f16x8 qf[4];
#pragma unroll
  for (int t = 0; t < 4; ++t)
    qf[t] = *(const f16x8*)(Qh + qbase + 16 * t + 8 * h5);

  f32x16 o0, o1;
#pragma unroll
  for (int r = 0; r < 16; ++r) { o0[r] = 0.f; o1[r] = 0.f; }
  float negm = 0.f;   // -m (running max in exp2 domain); m starts at 0
  float lsum = 0.f;

  // staging: 2 keys / 2 d-rows per thread, 16B chunks, incremental pointers
  const int keyA = tid >> 3;
  const int off8 = (tid & 7) * 8;
  const f16* kp = Kh + (size_t)(b * S + keyA) * D + h * 64 + off8;
  const f16* vp = Vtg + (size_t)bh * 64 * 2048 + (size_t)keyA * 2048 + off8;

  const auto pv_step = [&](const f32x16& s, const int koff) {
#pragma unroll
    for (int tp = 0; tp < 2; ++tp) {
      unsigned int u0 = pkrtz(s[8 * tp + 0], s[8 * tp + 1]);  // keys (h5=0): 0,1 | (h5=1): 4,5
      unsigned int u1 = pkrtz(s[8 * tp + 2], s[8 * tp + 3]);
      unsigned int u2 = pkrtz(s[8 * tp + 4], s[8 * tp + 5]);  // keys 8,9 | 12,13
      unsigned int u3 = pkrtz(s[8 * tp + 6], s[8 * tp + 7]);
      auto r0 = __builtin_amdgcn_permlane32_swap(u0, u2, false, false);
      auto r1 = __builtin_amdgcn_permlane32_swap(u1, u3, false, false);
      union { f16x8 v; unsigned int u[4]; } pf;
      pf.u[0] = r0[0];  // k 0..1 (own) | 8..9 (partner)
      pf.u[1] = r1[0];
      pf.u[2] = r0[1];  // k 4..5 (partner) | 12..13 (own)
      pf.u[3] = r1[1];
      f16x8 v0 = *(const f16x8*)(VtL + l31 * KROW + koff + 32 * tp + 16 * h5);
      f16x8 v1 = *(const f16x8*)(VtL + (32 + l31) * KROW + koff + 32 * tp + 16 * h5);
      o0 = __builtin_amdgcn_mfma_f32_32x32x16_f16(v0, pf.v, o0, 0, 0, 0);
      o1 = __builtin_amdgcn_mfma_f32_32x32x16_f16(v1, pf.v, o1, 0, 0, 0);
    }
  };

#define SV(i) ((i) < 16 ? s0[(i) & 15] : s1[(i) & 15])

  for (int it = 0; it < 32; ++it) {
    f16x8 rK0 = *(const f16x8*)kp;
    f16x8 rK1 = *(const f16x8*)(kp + (size_t)32 * D);
    f16x8 rV0 = *(const f16x8*)vp;
    f16x8 rV1 = *(const f16x8*)(vp + (size_t)32 * 2048);
    kp += (size_t)64 * D;
    vp += 64;

    __syncthreads();
    *(f16x8*)(KL + keyA * KROW + off8 * 2)         = rK0;
    *(f16x8*)(KL + (keyA + 32) * KROW + off8 * 2)  = rK1;
    *(f16x8*)(VtL + keyA * KROW + off8 * 2)        = rV0;
    *(f16x8*)(VtL + (keyA + 32) * KROW + off8 * 2) = rV1;
    __syncthreads();

    // ---- scores^T - m  (acc init = -m; exp2 domain) ----
    f32x16 s0, s1;
#pragma unroll
    for (int r = 0; r < 16; ++r) { s0[r] = negm; s1[r] = negm; }
#pragma unroll
    for (int t = 0; t < 4; ++t) {
      f16x8 a0 = *(const f16x8*)(KL + l31 * KROW + 32 * t + 16 * h5);
      f16x8 a1 = *(const f16x8*)(KL + (32 + l31) * KROW + 32 * t + 16 * h5);
      s0 = __builtin_amdgcn_mfma_f32_32x32x16_f16(a0, qf[t], s0, 0, 0, 0);
      s1 = __builtin_amdgcn_mfma_f32_32x32x16_f16(a1, qf[t], s1, 0, 0, 0);
    }

    // ---- relative-max via max3 tree (s regs already hold score - m) ----
    float a[12];
#pragma unroll
    for (int r = 0; r < 10; ++r)
      a[r] = fmaxf(fmaxf(SV(3 * r), SV(3 * r + 1)), SV(3 * r + 2));  // v_max3
    a[10] = SV(30); a[11] = SV(31);
    float b4[4];
#pragma unroll
    for (int r = 0; r < 4; ++r)
      b4[r] = fmaxf(fmaxf(a[3 * r], a[3 * r + 1]), a[3 * r + 2]);
    float tr = fmaxf(fmaxf(b4[0], b4[1]), fmaxf(b4[2], b4[3]));
    tr = fmaxf(tr, __shfl_xor(tr, 32));

    if (!__all(tr <= 8.0f)) {       // wave-uniform rescale (rare)
      const float d = fmaxf(tr, 0.f);
      const float fr = exp2f(-d);
      lsum *= fr;
#pragma unroll
      for (int r = 0; r < 16; ++r) { o0[r] *= fr; o1[r] *= fr; }
      negm -= d;
#pragma unroll
      for (int r = 0; r < 16; ++r) { s0[r] -= d; s1[r] -= d; }
    }

    // ---- P = exp2(s_rel); row-sum tree ----
#pragma unroll
    for (int r = 0; r < 16; ++r) s0[r] = exp2f(s0[r]);
#pragma unroll
    for (int r = 0; r < 16; ++r) s1[r] = exp2f(s1[r]);
    float ts[16];
#pragma unroll
    for (int r = 0; r < 16; ++r) ts[r] = s0[r] + s1[r];
#pragma unroll
    for (int st = 8; st >= 1; st >>= 1)
#pragma unroll
      for (int r = 0; r < st; ++r) ts[r] += ts[r + st];
    lsum += ts[0] + __shfl_xor(ts[0], 32);

    pv_step(s0, 0);
    pv_step(s1, 64);
  }
#undef SV

  // ---- epilogue: O^T -> LDS transpose -> coalesced f16 stores ----
  __syncthreads();
  const float inv = 1.f / lsum;
  float* owp = Ow + w * 32 * OWST;
#pragma unroll
  for (int r = 0; r < 16; ++r) {
    const int d = (r & 3) + 8 * (r >> 2) + 4 * h5;
    owp[l31 * OWST + d]      = o0[r] * inv;
    owp[l31 * OWST + d + 32] = o1[r] * inv;
  }
  __syncthreads();
#pragma unroll
  for (int it = 0; it < 8; ++it) {
    const int row = it * 4 + (lane >> 4);
    const int col = (lane & 15) * 4;
    float4 val = *(float4*)(owp + row * OWST + col);
    const int token = b * S + qt * 128 + w * 32 + row;
    f16x4 hv;
    hv[0] = (f16)val.x; hv[1] = (f16)val.y; hv[2] = (f16)val.z; hv[3] = (f16)val.w;
    *(f16x4*)(Cc + (size_t)token * D + h * 64 + col) = hv;
  }
}

// ---------------------------------------------------------------------------

extern "C" void kernel_launch(void* const* d_in, const int* in_sizes, int n_in,
                              void* d_out, int out_size, void* d_ws, size_t ws_size,
                              hipStream_t stream) {
  const float* X  = (const float*)d_in[0];
  const float* Wq = (const float*)d_in[1];
  const float* bq = (const float*)d_in[2];
  const float* Wk = (const float*)d_in[3];
  const float* bk = (const float*)d_in[4];
  const float* Wv = (const float*)d_in[5];
  const float* bv = (const float*)d_in[6];
  const float* Wo = (const float*)d_in[7];
  const float* bo = (const float*)d_in[8];
  float* out = (float*)d_out;

  const int B = 2, S = 2048, D = 1024;
  const int M = B * S;                 // 4096
  const size_t MD = (size_t)M * D;     // 4M elements

  f16* Xh  = (f16*)d_ws;               // 8 MB each MD-sized f16 buffer
  f16* Qh  = Xh + MD;
  f16* Kh  = Qh + MD;
  f16* Vtg = Kh + MD;
  f16* Cc  = Vtg + MD;
  f16* Wt  = Cc + MD;                  // 4 x D*D f16 = 8 MB
  f16* Wts[4];
  for (int i = 0; i < 4; ++i) Wts[i] = Wt + (size_t)i * D * D;

  to_f16_kernel<<<dim3(MD / (256 * 8)), 256, 0, stream>>>(X, Xh);
  tconv_kernel<<<dim3(D / 32, D / 32, 4), 256, 0, stream>>>(
      Wq, Wk, Wv, Wo, Wts[0], Wts[1], Wts[2], Wts[3], D, D);

  gemm_qkv_f16<<<dim3(D / 128, M / 128, 3), 256, 0, stream>>>(
      Xh, Wts[0], Wts[1], Wts[2], bq, bk, bv, Qh, Kh, Vtg, M, D, D);

  flash_f16_kernel<<<dim3(16, 32), 256, 0, stream>>>(Qh, Kh, Vtg, Cc);

  gemm_out_f16<<<dim3(D / 128, M / 128, 1), 256, 0, stream>>>(
      Cc, Wts[3], bo, out, M, D, D);
}